// Round 15
// baseline (440.247 us; speedup 1.0000x reference)
//
#include <hip/hip_runtime.h>
#include <cmath>

// VQ-VAE quantization forward: B=64, K=1024, D=128, H=W=32.
// Ref model (6 rounds of absmax triangulation): q_k = fl32(fl32(A - fl32(2*B_k)) + C_k),
// first-index argmin, B = single-accumulator SEQUENTIAL FMA over d.
// A = sum(z*z,-1) sequential; C = sum(emb*emb,-1) pairwise-8.
// out0 = fl(fl(e-z)+z); out1 = e. Exact chains pinned with empty-asm barriers.
//
// R15 = R14 (213us dispatch, 16-wave blocks, VGPR 52 no-spill) minus s_zT:
// z is read from GLOBAL (the R9/R10-verified absmax-0 variant). LDS drops
// 108KB -> ~40KB so TWO 1024-thread blocks co-reside per CU (thread-slot
// limit 2048): 8 waves/SIMD, one block's head/tail/barrier-joins hide under
// the other's coarse rounds. R14's key new fact makes this safe where R9
// wasn't: at NW=16 the live set is 52, and the 2-resident RA target is
// 512/8 = 64 >= 52 => no spill required (falsifier: FETCH >100MB = spill).
//  * A-frags built from global z columns (R10 code, coalesced 4B x 16 lanes).
//  * refinement A/B chains read global zrow (R10 code, unroll-8 loads under
//    the pinned chain); epilogue z from global (256B/row coalesced).
// Verbatim from R14: half-split rounds (wave-half h computes tiles {2h,2h+1}),
// T14 issue-early/write-late staging, branchless packed-u32 top-4 selection
// (KMASK truncation << MARGIN), cross-half LDS combine (s_gmin/s_pk64, no
// atomics), snorm prologue (pinned pairwise-8, bit-identical), fragment
// bijection, C/D map, f2bf bits, exact pinned A/B/epilogue chains, packed
// (q,k) u64 min, first-index tie-break.

#define D_DIM   128
#define K_CODES 1024
#define HW_SZ   1024
#define N_PIX   65536
#define OUT_OFF ((size_t)N_PIX * D_DIM)

#define PXB     128                     // pixels per block
#define NW      16                      // waves per block (1024 threads)
#define NTILE   (K_CODES / 16)          // 64 code-tiles
#define TPR     4                       // tiles staged per round
#define ROUNDS  (NTILE / TPR)           // 16
#define MARGIN  2.0e-3f                 // coarse->exact window
#define KMASK   0xFFFFFC00u             // key bits (code in low 10)

typedef float  f32x4 __attribute__((ext_vector_type(4)));
typedef short  s16x8 __attribute__((ext_vector_type(8)));
typedef unsigned short u16x8 __attribute__((ext_vector_type(8)));

// --- compiler-proof fp32 ops: result pinned in a VGPR via empty asm ---
__device__ __forceinline__ float fmul_x(float a, float b) {
    float r = a * b; asm volatile("" : "+v"(r)); return r;
}
__device__ __forceinline__ float fadd_x(float a, float b) {
    float r = a + b; asm volatile("" : "+v"(r)); return r;
}
__device__ __forceinline__ float fsub_x(float a, float b) {
    float r = a - b; asm volatile("" : "+v"(r)); return r;
}
__device__ __forceinline__ float ffma_x(float a, float b, float c) {
    float r = fmaf(a, b, c); asm volatile("" : "+v"(r)); return r;
}

// RNE float -> bf16 bits (inputs are normal floats here)
__device__ __forceinline__ unsigned short f2bf(float f) {
    unsigned u = __float_as_uint(f);
    u += 0x7FFFu + ((u >> 16) & 1u);
    return (unsigned short)(u >> 16);
}

// monotone float<->u32 order-preserving transform (no NaNs in play)
__device__ __forceinline__ unsigned key32(float t) {
    const unsigned u = __float_as_uint(t);
    return u ^ (unsigned)(((int)u >> 31) | (int)0x80000000);
}
__device__ __forceinline__ float unkey32(unsigned k) {
    const unsigned u = (k & 0x80000000u) ? (k ^ 0x80000000u) : ~k;
    return __uint_as_float(u);
}

// ---- prologue: snorm table, pairwise-8 pinned chain VERBATIM, once ----
__global__ __launch_bounds__(256) void snorm_pre(
    const float* __restrict__ emb, float* __restrict__ ws)
{
#pragma clang fp contract(off)
    const int k = blockIdx.x * 256 + threadIdx.x;   // 0..1023
    const float* row = emb + (size_t)k * D_DIM;
    float r[8];
    #pragma unroll
    for (int j = 0; j < 8; ++j) r[j] = fmul_x(row[j], row[j]);
    for (int i = 8; i < D_DIM; i += 8) {
        #pragma unroll
        for (int j = 0; j < 8; ++j)
            r[j] = fadd_x(r[j], fmul_x(row[i + j], row[i + j]));
    }
    const float s01 = fadd_x(r[0], r[1]), s23 = fadd_x(r[2], r[3]);
    const float s45 = fadd_x(r[4], r[5]), s67 = fadd_x(r[6], r[7]);
    ws[k] = fadd_x(fadd_x(s01, s23), fadd_x(s45, s67));
}

// fragment geometry for frag id f (0..1023): tile tt, d-block dt, frag-lane l
__device__ __forceinline__ const float* frag_src(
    const float* __restrict__ emb, const int Tbase, const int f)
{
    const int tt = f >> 8;
    const int dt = (f >> 6) & 3;
    const int l  = f & 63;
    const int code = (Tbase + tt) * 16 + (l & 15);
    const int d0   = dt * 32 + ((l >> 4) & 3) * 8;
    return emb + (size_t)code * D_DIM + d0;
}

__global__ __launch_bounds__(1024) void vq_fused(
    const float* __restrict__ z_e,
    const float* __restrict__ emb,
    const float* __restrict__ sn_ws,
    float* __restrict__ out)
{
#pragma clang fp contract(off)
    __shared__ alignas(16) unsigned short e_s[2][TPR * 2048]; // 32768 B frag dbuf
    __shared__ float snorm[K_CODES];                          // 4096 B
    __shared__ unsigned s_gmin[2][PXB];                       // 1024 B per-half row mins
    __shared__ unsigned long long s_pk64[2][PXB];             // 2048 B per-half (q,k)
    __shared__ int s_kwin[PXB];                               // 512 B
    // total ~40 KB => 2 blocks/CU (thread-slot limited), 8 waves/SIMD

    const int px  = threadIdx.x;                // lane 0..63
    const int ky  = threadIdx.y;                // wave 0..15
    const int tid = ky * 64 + px;               // 0..1023

    const int p0  = blockIdx.x * PXB;
    const int b   = p0 >> 10;
    const int hw0 = p0 & (HW_SZ - 1);
    const float* zblk = z_e + (size_t)b * (D_DIM * HW_SZ) + hw0;

    // ---- snorm: coalesced load of the precomputed table (identical bits) ----
    snorm[tid] = sn_ws[tid];

    // ---- round-0 e-frags: exactly one frag per thread ----
    {
        const float* s = frag_src(emb, 0, tid);
        const f32x4 va0 = *(const f32x4*)(s);
        const f32x4 va1 = *(const f32x4*)(s + 4);
        u16x8 o;
        o[0] = f2bf(va0[0]); o[1] = f2bf(va0[1]); o[2] = f2bf(va0[2]); o[3] = f2bf(va0[3]);
        o[4] = f2bf(va1[0]); o[5] = f2bf(va1[1]); o[6] = f2bf(va1[2]); o[7] = f2bf(va1[3]);
        *(u16x8*)(e_s[0] + (size_t)tid * 8) = o;
    }

    // ---- build A-frags from GLOBAL z: wave (ky&7) owns px rows
    //      [(ky&7)*16, +16); lane reads its own pixel column ----
    const int lm = px & 15;                     // 16-index (A row / B col)
    const int lg = px >> 4;                     // d-slice group 0..3
    const int pxbase = (ky & 7) * 16;
    const int half = ky >> 3;                   // code-half within each round

    const float* zcol = zblk + (pxbase + lm);   // this lane's pixel column
    s16x8 afr[4];
    #pragma unroll
    for (int dt = 0; dt < 4; ++dt) {
        s16x8 a;
        #pragma unroll
        for (int j = 0; j < 8; ++j) {
            const int d = dt * 32 + lg * 8 + j;
            a[j] = (short)f2bf(zcol[(size_t)d * HW_SZ]);
        }
        afr[dt] = a;
    }

    __syncthreads();                            // snorm + round-0 frags visible

    // per-(px-row, column, half) 4-deep sorted top lists, packed u32 (key|code)
    unsigned pk[4][4];
    #pragma unroll
    for (int r = 0; r < 4; ++r) {
        #pragma unroll
        for (int s = 0; s < 4; ++s) pk[r][s] = 0xFFFFFFFFu;
    }

    // ====== coarse pass: T14-split staging + MFMA + branchless selection ======
    {
        int buf = 0;
        #pragma unroll 1
        for (int rnd = 0; rnd < ROUNDS; ++rnd) {
            // (a) ISSUE next round's global load (1 frag/thread)
            f32x4 va0, va1;
            const bool pre = (rnd + 1 < ROUNDS);
            if (pre) {
                const float* s = frag_src(emb, (rnd + 1) * TPR, tid);
                va0 = *(const f32x4*)(s);
                va1 = *(const f32x4*)(s + 4);
            }
            // (b) compute this wave-half's 2 tiles from e_s[buf]
            #pragma unroll
            for (int ti = 0; ti < 2; ++ti) {
                const int tl = half * 2 + ti;
                const unsigned short* fb = e_s[buf] + (size_t)tl * 2048 + (size_t)px * 8;
                const s16x8 c0 = *(const s16x8*)(fb);
                const s16x8 c1 = *(const s16x8*)(fb + 512);
                const s16x8 c2 = *(const s16x8*)(fb + 1024);
                const s16x8 c3 = *(const s16x8*)(fb + 1536);
                f32x4 a0 = {0.f, 0.f, 0.f, 0.f};
                f32x4 a1 = {0.f, 0.f, 0.f, 0.f};
                a0 = __builtin_amdgcn_mfma_f32_16x16x32_bf16(afr[0], c0, a0, 0, 0, 0);
                a0 = __builtin_amdgcn_mfma_f32_16x16x32_bf16(afr[1], c1, a0, 0, 0, 0);
                a1 = __builtin_amdgcn_mfma_f32_16x16x32_bf16(afr[2], c2, a1, 0, 0, 0);
                a1 = __builtin_amdgcn_mfma_f32_16x16x32_bf16(afr[3], c3, a1, 0, 0, 0);
                const int code = (rnd * TPR + tl) * 16 + lm;
                const float sn = snorm[code];
                #pragma unroll
                for (int r = 0; r < 4; ++r) {
                    const float t = fmaf(-2.f, a0[r] + a1[r], sn);
                    const unsigned p = (key32(t) & KMASK) | (unsigned)code;
                    // branchless sorted insert (bubble network, ascending)
                    const unsigned m0 = min(pk[r][0], p), M0 = max(pk[r][0], p);
                    pk[r][0] = m0;
                    const unsigned m1 = min(pk[r][1], M0), M1 = max(pk[r][1], M0);
                    pk[r][1] = m1;
                    const unsigned m2 = min(pk[r][2], M1), M2 = max(pk[r][2], M1);
                    pk[r][2] = m2;
                    pk[r][3] = min(pk[r][3], M2);
                }
            }
            // (c) WRITE the prefetched frag (vmcnt wait lands here, post-compute)
            if (pre) {
                u16x8 o;
                o[0] = f2bf(va0[0]); o[1] = f2bf(va0[1]); o[2] = f2bf(va0[2]); o[3] = f2bf(va0[3]);
                o[4] = f2bf(va1[0]); o[5] = f2bf(va1[1]); o[6] = f2bf(va1[2]); o[7] = f2bf(va1[3]);
                *(u16x8*)(e_s[buf ^ 1] + (size_t)tid * 8) = o;
            }
            __syncthreads();                    // next buf staged; this buf free
            buf ^= 1;
        }
    }

    // ---- per-half per-row min via 16-lane shfl, then LDS slot ----
    #pragma unroll
    for (int r = 0; r < 4; ++r) {
        unsigned g = pk[r][0];
        #pragma unroll
        for (int mask = 1; mask < 16; mask <<= 1) {
            const unsigned o = (unsigned)__shfl_xor((int)g, mask, 64);
            g = min(g, o);
        }
        if (lm == 0) s_gmin[half][pxbase + lg * 4 + r] = g;
    }
    __syncthreads();

    // ---- per-row threshold from cross-half min ----
    unsigned thrk[4];
    #pragma unroll
    for (int r = 0; r < 4; ++r) {
        const int prow = pxbase + lg * 4 + r;
        const unsigned g = min(s_gmin[0][prow], s_gmin[1][prow]);
        const float tlo = unkey32(g & KMASK);   // best-t lower bound
        thrk[r] = key32(tlo + MARGIN) & KMASK;  // window threshold in key space
    }

    // ---- per-lane exact refinement of qualifying candidates + u64 combine ----
    #pragma unroll
    for (int r = 0; r < 4; ++r) {
        const int prow = pxbase + lg * 4 + r;
        unsigned long long packq = ~0ULL;
        const bool any = ((pk[r][0] & KMASK) <= thrk[r]) |
                         ((pk[r][1] & KMASK) <= thrk[r]) |
                         ((pk[r][2] & KMASK) <= thrk[r]) |
                         ((pk[r][3] & KMASK) <= thrk[r]);
        if (any) {
            const float* zrow = zblk + prow;    // lane's pixel, global fp32 z
            // A: sequential over d (chain kept honest; value cancels per-pixel).
            const float z0 = zrow[0];
            float A32 = fmul_x(z0, z0);
            #pragma unroll 8
            for (int d = 1; d < D_DIM; ++d) {
                const float zd = zrow[(size_t)d * HW_SZ];
                A32 = fadd_x(A32, fmul_x(zd, zd));
            }
            #pragma unroll
            for (int s = 0; s < 4; ++s) {
                if ((pk[r][s] & KMASK) <= thrk[r]) {
                    const int kc = (int)(pk[r][s] & 1023u);
                    const float* e = emb + (size_t)kc * D_DIM;
                    // B: GEMM-style single-accumulator SEQUENTIAL FMA over d.
                    float B32 = 0.f;
                    #pragma unroll 8
                    for (int d = 0; d < D_DIM; ++d)
                        B32 = ffma_x(zrow[(size_t)d * HW_SZ], e[d], B32);
                    const float twoB = fmul_x(2.0f, B32);      // exact
                    const float q    = fadd_x(fsub_x(A32, twoB), snorm[kc]);
                    // q = ||z-e||^2 ~ ||z||^2 > 0: positive-float uint order OK.
                    const unsigned long long p =
                        ((unsigned long long)__float_as_uint(q) << 32) |
                        (unsigned)kc;          // low bits = k: first-index tie-break
                    packq = (p < packq) ? p : packq;
                }
            }
        }
        // convergent 16-lane min-combine of packed (q,k)
        #pragma unroll
        for (int mask = 1; mask < 16; mask <<= 1) {
            const unsigned long long o = __shfl_xor(packq, mask, 64);
            packq = (o < packq) ? o : packq;
        }
        if (lm == 0) s_pk64[half][prow] = packq;
    }
    __syncthreads();

    // ---- cross-half final argmin ----
    if (tid < PXB) {
        const unsigned long long p0q = s_pk64[0][tid];
        const unsigned long long p1q = s_pk64[1][tid];
        s_kwin[tid] = (int)((p0q < p1q ? p0q : p1q) & 0xffffffffu);
    }
    __syncthreads();

    // ---- epilogue: out0 = fl(fl(e-z)+z) (pinned), out1 = e; z from global ----
    const int p  = tid & 127;                   // pixel
    const int dg = tid >> 7;                    // d-eighth 0..7
    const int kwin = s_kwin[p];
    const float* er = emb + (size_t)kwin * D_DIM + dg * 16;
    const float* zp = zblk + p;
    float* o0 = out + (size_t)b * (D_DIM * HW_SZ) + hw0 + p;
    float* o1 = o0 + OUT_OFF;
    #pragma unroll
    for (int i = 0; i < 4; ++i) {
        const f32x4 e4 = *(const f32x4*)(er + i * 4);
        #pragma unroll
        for (int j = 0; j < 4; ++j) {
            const int d = dg * 16 + i * 4 + j;
            const float zv = zp[(size_t)d * HW_SZ];
            o0[(size_t)d * HW_SZ] = fadd_x(fsub_x(e4[j], zv), zv);
            o1[(size_t)d * HW_SZ] = e4[j];
        }
    }
}

extern "C" void kernel_launch(void* const* d_in, const int* in_sizes, int n_in,
                              void* d_out, int out_size, void* d_ws, size_t ws_size,
                              hipStream_t stream)
{
    const float* z_e = (const float*)d_in[0];
    const float* emb = (const float*)d_in[1];
    float* out = (float*)d_out;
    float* sn_ws = (float*)d_ws;
    (void)in_sizes; (void)n_in; (void)out_size; (void)ws_size;

    snorm_pre<<<dim3(K_CODES / 256), dim3(256), 0, stream>>>(emb, sn_ws);
    vq_fused<<<dim3(N_PIX / PXB), dim3(64, NW), 0, stream>>>(z_e, emb, sn_ws, out);
}

// Round 16
// 260.535 us; speedup vs baseline: 1.6898x; 1.6898x over previous
//
#include <hip/hip_runtime.h>
#include <cmath>

// VQ-VAE quantization forward: B=64, K=1024, D=128, H=W=32.
// Ref model (6 rounds of absmax triangulation): q_k = fl32(fl32(A - fl32(2*B_k)) + C_k),
// first-index argmin, B = single-accumulator SEQUENTIAL FMA over d.
// A = sum(z*z,-1) sequential; C = sum(emb*emb,-1) pairwise-8.
// out0 = fl(fl(e-z)+z); out1 = e. Exact chains pinned with empty-asm barriers.
//
// R16 = R14 (best: 213us dispatch, 16-wave blocks, big-LDS generous-RA regime)
// + two local cuts. R15 proved: (a) 1024-thread blocks never co-reside 2/CU
// (occupancy 38.7 ~= R14's 41.8 despite 40KB LDS), (b) small-LDS => stingy-RA
// poison, third occurrence (VGPR 40 < live set). So occupancy is capped at
// 4 waves/SIMD and the lever is per-block serial time:
//  * A32 PRECOMPUTED per block into s_A[128]: tid<128 run the VERBATIM pinned
//    sequential-d chain from s_zT right after the transpose barrier (overlaps
//    round-0 compute; visible to refinement via the round barriers). Cuts the
//    4x254-op pinned chains all 16 waves issued (~16K slots/block -> ~0.5K).
//    Same inputs, same order => bit-identical A32.
//  * TPR 16->8 tiles/round (ROUNDS 8): halves barrier count, doubles
//    independent tiles per interval (4/wave-half => deeper ds_read/MFMA ILP).
//    e_s = 2x32KB; LDS ~141KB — deeper in the proven generous-RA regime.
//    Staging = 2 frags/thread with the same T14 issue-early/write-late split.
// Verbatim from R14: half-split rounds, branchless packed-u32 top-4 selection
// (KMASK truncation << MARGIN), cross-half LDS combine (s_gmin/s_pk64), snorm
// prologue (pinned pairwise-8), s_zT transpose, fragment bijection, C/D map,
// f2bf bits, exact pinned B/epilogue chains, packed (q,k) u64 min,
// first-index tie-break.

#define D_DIM   128
#define K_CODES 1024
#define HW_SZ   1024
#define N_PIX   65536
#define OUT_OFF ((size_t)N_PIX * D_DIM)

#define PXB     128                     // pixels per block
#define NW      16                      // waves per block (1024 threads)
#define NTILE   (K_CODES / 16)          // 64 code-tiles
#define TPR     8                       // tiles staged per round
#define ROUNDS  (NTILE / TPR)           // 8
#define ZLD     132                     // padded z row (floats)
#define MARGIN  2.0e-3f                 // coarse->exact window
#define KMASK   0xFFFFFC00u             // key bits (code in low 10)

typedef float  f32x4 __attribute__((ext_vector_type(4)));
typedef short  s16x8 __attribute__((ext_vector_type(8)));
typedef unsigned short u16x8 __attribute__((ext_vector_type(8)));

// --- compiler-proof fp32 ops: result pinned in a VGPR via empty asm ---
__device__ __forceinline__ float fmul_x(float a, float b) {
    float r = a * b; asm volatile("" : "+v"(r)); return r;
}
__device__ __forceinline__ float fadd_x(float a, float b) {
    float r = a + b; asm volatile("" : "+v"(r)); return r;
}
__device__ __forceinline__ float fsub_x(float a, float b) {
    float r = a - b; asm volatile("" : "+v"(r)); return r;
}
__device__ __forceinline__ float ffma_x(float a, float b, float c) {
    float r = fmaf(a, b, c); asm volatile("" : "+v"(r)); return r;
}

// RNE float -> bf16 bits (inputs are normal floats here)
__device__ __forceinline__ unsigned short f2bf(float f) {
    unsigned u = __float_as_uint(f);
    u += 0x7FFFu + ((u >> 16) & 1u);
    return (unsigned short)(u >> 16);
}

// monotone float<->u32 order-preserving transform (no NaNs in play)
__device__ __forceinline__ unsigned key32(float t) {
    const unsigned u = __float_as_uint(t);
    return u ^ (unsigned)(((int)u >> 31) | (int)0x80000000);
}
__device__ __forceinline__ float unkey32(unsigned k) {
    const unsigned u = (k & 0x80000000u) ? (k ^ 0x80000000u) : ~k;
    return __uint_as_float(u);
}

// ---- prologue: snorm table, pairwise-8 pinned chain VERBATIM, once ----
__global__ __launch_bounds__(256) void snorm_pre(
    const float* __restrict__ emb, float* __restrict__ ws)
{
#pragma clang fp contract(off)
    const int k = blockIdx.x * 256 + threadIdx.x;   // 0..1023
    const float* row = emb + (size_t)k * D_DIM;
    float r[8];
    #pragma unroll
    for (int j = 0; j < 8; ++j) r[j] = fmul_x(row[j], row[j]);
    for (int i = 8; i < D_DIM; i += 8) {
        #pragma unroll
        for (int j = 0; j < 8; ++j)
            r[j] = fadd_x(r[j], fmul_x(row[i + j], row[i + j]));
    }
    const float s01 = fadd_x(r[0], r[1]), s23 = fadd_x(r[2], r[3]);
    const float s45 = fadd_x(r[4], r[5]), s67 = fadd_x(r[6], r[7]);
    ws[k] = fadd_x(fadd_x(s01, s23), fadd_x(s45, s67));
}

// fragment geometry for frag id f (0..2047): tile tt, d-block dt, frag-lane l
__device__ __forceinline__ const float* frag_src(
    const float* __restrict__ emb, const int Tbase, const int f)
{
    const int tt = f >> 8;                      // 0..TPR-1
    const int dt = (f >> 6) & 3;
    const int l  = f & 63;
    const int code = (Tbase + tt) * 16 + (l & 15);
    const int d0   = dt * 32 + ((l >> 4) & 3) * 8;
    return emb + (size_t)code * D_DIM + d0;
}

__global__ __launch_bounds__(1024) void vq_fused(
    const float* __restrict__ z_e,
    const float* __restrict__ emb,
    const float* __restrict__ sn_ws,
    float* __restrict__ out)
{
#pragma clang fp contract(off)
    __shared__ float s_zT[PXB][ZLD];                          // 67584 B fp32 z, [px][d]
    __shared__ alignas(16) unsigned short e_s[2][TPR * 2048]; // 65536 B frag dbuf
    __shared__ float snorm[K_CODES];                          // 4096 B
    __shared__ float s_A[PXB];                                // 512 B per-pixel A32
    __shared__ unsigned s_gmin[2][PXB];                       // 1024 B per-half row mins
    __shared__ unsigned long long s_pk64[2][PXB];             // 2048 B per-half (q,k)
    __shared__ int s_kwin[PXB];                               // 512 B
    // total ~141 KB => 1 block/CU, generous-RA regime (the only no-spill one)

    const int px  = threadIdx.x;                // lane 0..63
    const int ky  = threadIdx.y;                // wave 0..15
    const int tid = ky * 64 + px;               // 0..1023

    const int p0  = blockIdx.x * PXB;
    const int b   = p0 >> 10;
    const int hw0 = p0 & (HW_SZ - 1);
    const float* zbase = z_e + (size_t)b * (D_DIM * HW_SZ) + hw0;

    // ---- snorm: coalesced load of the precomputed table (identical bits) ----
    snorm[tid] = sn_ws[tid];

    // ---- z stage: global [d][128 px] -> s_zT[px][d] (transpose) ----
    #pragma unroll
    for (int r = 0; r < 4; ++r) {
        const int idx = r * 1024 + tid;         // 0..4095
        const int d   = idx >> 5;               // 0..127
        const int i4  = (idx & 31) * 4;         // pixel group
        const f32x4 v = *(const f32x4*)(zbase + (size_t)d * HW_SZ + i4);
        s_zT[i4 + 0][d] = v[0];
        s_zT[i4 + 1][d] = v[1];
        s_zT[i4 + 2][d] = v[2];
        s_zT[i4 + 3][d] = v[3];
    }

    // ---- round-0 e-frags: two frags per thread ----
    {
        const float* sa = frag_src(emb, 0, tid);
        const float* sb = frag_src(emb, 0, 1024 + tid);
        const f32x4 va0 = *(const f32x4*)(sa);
        const f32x4 va1 = *(const f32x4*)(sa + 4);
        const f32x4 vb0 = *(const f32x4*)(sb);
        const f32x4 vb1 = *(const f32x4*)(sb + 4);
        u16x8 o;
        o[0] = f2bf(va0[0]); o[1] = f2bf(va0[1]); o[2] = f2bf(va0[2]); o[3] = f2bf(va0[3]);
        o[4] = f2bf(va1[0]); o[5] = f2bf(va1[1]); o[6] = f2bf(va1[2]); o[7] = f2bf(va1[3]);
        *(u16x8*)(e_s[0] + (size_t)tid * 8) = o;
        o[0] = f2bf(vb0[0]); o[1] = f2bf(vb0[1]); o[2] = f2bf(vb0[2]); o[3] = f2bf(vb0[3]);
        o[4] = f2bf(vb1[0]); o[5] = f2bf(vb1[1]); o[6] = f2bf(vb1[2]); o[7] = f2bf(vb1[3]);
        *(u16x8*)(e_s[0] + (size_t)(1024 + tid) * 8) = o;
    }
    __syncthreads();                            // z + snorm + round-0 frags visible

    // ---- A32 precompute (overlaps round-0 compute of other waves):
    //      VERBATIM pinned sequential-d chain; visible to refinement via the
    //      round barriers below. Bit-identical to the per-lane version. ----
    if (tid < PXB) {
        const float z0 = s_zT[tid][0];
        float A32 = fmul_x(z0, z0);
        for (int d = 1; d < D_DIM; ++d) {
            const float zd = s_zT[tid][d];
            A32 = fadd_x(A32, fmul_x(zd, zd));
        }
        s_A[tid] = A32;
    }

    // ---- build A-frags: wave (ky&7) owns px rows [(ky&7)*16, +16) ----
    const int lm = px & 15;                     // 16-index (A row / B col)
    const int lg = px >> 4;                     // d-slice group 0..3
    const int pxbase = (ky & 7) * 16;
    const int half = ky >> 3;                   // code-half within each round

    s16x8 afr[4];
    #pragma unroll
    for (int dt = 0; dt < 4; ++dt) {
        const float* zr = &s_zT[pxbase + lm][dt * 32 + lg * 8];
        const f32x4 z0 = *(const f32x4*)zr;
        const f32x4 z1 = *(const f32x4*)(zr + 4);
        s16x8 a;
        a[0] = (short)f2bf(z0[0]); a[1] = (short)f2bf(z0[1]);
        a[2] = (short)f2bf(z0[2]); a[3] = (short)f2bf(z0[3]);
        a[4] = (short)f2bf(z1[0]); a[5] = (short)f2bf(z1[1]);
        a[6] = (short)f2bf(z1[2]); a[7] = (short)f2bf(z1[3]);
        afr[dt] = a;
    }

    // per-(px-row, column, half) 4-deep sorted top lists, packed u32 (key|code)
    unsigned pk[4][4];
    #pragma unroll
    for (int r = 0; r < 4; ++r) {
        #pragma unroll
        for (int s = 0; s < 4; ++s) pk[r][s] = 0xFFFFFFFFu;
    }

    // ====== coarse pass: T14-split staging + MFMA + branchless selection ======
    {
        int buf = 0;
        #pragma unroll 1
        for (int rnd = 0; rnd < ROUNDS; ++rnd) {
            // (a) ISSUE next round's global loads (2 frags/thread)
            f32x4 va0, va1, vb0, vb1;
            const bool pre = (rnd + 1 < ROUNDS);
            if (pre) {
                const float* sa = frag_src(emb, (rnd + 1) * TPR, tid);
                const float* sb = frag_src(emb, (rnd + 1) * TPR, 1024 + tid);
                va0 = *(const f32x4*)(sa);
                va1 = *(const f32x4*)(sa + 4);
                vb0 = *(const f32x4*)(sb);
                vb1 = *(const f32x4*)(sb + 4);
            }
            // (b) compute this wave-half's 4 tiles from e_s[buf]
            #pragma unroll
            for (int ti = 0; ti < 4; ++ti) {
                const int tl = half * 4 + ti;
                const unsigned short* fb = e_s[buf] + (size_t)tl * 2048 + (size_t)px * 8;
                const s16x8 c0 = *(const s16x8*)(fb);
                const s16x8 c1 = *(const s16x8*)(fb + 512);
                const s16x8 c2 = *(const s16x8*)(fb + 1024);
                const s16x8 c3 = *(const s16x8*)(fb + 1536);
                f32x4 a0 = {0.f, 0.f, 0.f, 0.f};
                f32x4 a1 = {0.f, 0.f, 0.f, 0.f};
                a0 = __builtin_amdgcn_mfma_f32_16x16x32_bf16(afr[0], c0, a0, 0, 0, 0);
                a0 = __builtin_amdgcn_mfma_f32_16x16x32_bf16(afr[1], c1, a0, 0, 0, 0);
                a1 = __builtin_amdgcn_mfma_f32_16x16x32_bf16(afr[2], c2, a1, 0, 0, 0);
                a1 = __builtin_amdgcn_mfma_f32_16x16x32_bf16(afr[3], c3, a1, 0, 0, 0);
                const int code = (rnd * TPR + tl) * 16 + lm;
                const float sn = snorm[code];
                #pragma unroll
                for (int r = 0; r < 4; ++r) {
                    const float t = fmaf(-2.f, a0[r] + a1[r], sn);
                    const unsigned p = (key32(t) & KMASK) | (unsigned)code;
                    // branchless sorted insert (bubble network, ascending)
                    const unsigned m0 = min(pk[r][0], p), M0 = max(pk[r][0], p);
                    pk[r][0] = m0;
                    const unsigned m1 = min(pk[r][1], M0), M1 = max(pk[r][1], M0);
                    pk[r][1] = m1;
                    const unsigned m2 = min(pk[r][2], M1), M2 = max(pk[r][2], M1);
                    pk[r][2] = m2;
                    pk[r][3] = min(pk[r][3], M2);
                }
            }
            // (c) WRITE the prefetched frags (vmcnt waits land here, post-compute)
            if (pre) {
                u16x8 o;
                o[0] = f2bf(va0[0]); o[1] = f2bf(va0[1]); o[2] = f2bf(va0[2]); o[3] = f2bf(va0[3]);
                o[4] = f2bf(va1[0]); o[5] = f2bf(va1[1]); o[6] = f2bf(va1[2]); o[7] = f2bf(va1[3]);
                *(u16x8*)(e_s[buf ^ 1] + (size_t)tid * 8) = o;
                o[0] = f2bf(vb0[0]); o[1] = f2bf(vb0[1]); o[2] = f2bf(vb0[2]); o[3] = f2bf(vb0[3]);
                o[4] = f2bf(vb1[0]); o[5] = f2bf(vb1[1]); o[6] = f2bf(vb1[2]); o[7] = f2bf(vb1[3]);
                *(u16x8*)(e_s[buf ^ 1] + (size_t)(1024 + tid) * 8) = o;
            }
            __syncthreads();                    // next buf staged; this buf free
            buf ^= 1;
        }
    }

    // ---- per-half per-row min via 16-lane shfl, then LDS slot ----
    #pragma unroll
    for (int r = 0; r < 4; ++r) {
        unsigned g = pk[r][0];
        #pragma unroll
        for (int mask = 1; mask < 16; mask <<= 1) {
            const unsigned o = (unsigned)__shfl_xor((int)g, mask, 64);
            g = min(g, o);
        }
        if (lm == 0) s_gmin[half][pxbase + lg * 4 + r] = g;
    }
    __syncthreads();

    // ---- per-row threshold from cross-half min ----
    unsigned thrk[4];
    #pragma unroll
    for (int r = 0; r < 4; ++r) {
        const int prow = pxbase + lg * 4 + r;
        const unsigned g = min(s_gmin[0][prow], s_gmin[1][prow]);
        const float tlo = unkey32(g & KMASK);   // best-t lower bound
        thrk[r] = key32(tlo + MARGIN) & KMASK;  // window threshold in key space
    }

    // ---- per-lane exact refinement of qualifying candidates + u64 combine ----
    #pragma unroll
    for (int r = 0; r < 4; ++r) {
        const int prow = pxbase + lg * 4 + r;
        unsigned long long packq = ~0ULL;
        const bool any = ((pk[r][0] & KMASK) <= thrk[r]) |
                         ((pk[r][1] & KMASK) <= thrk[r]) |
                         ((pk[r][2] & KMASK) <= thrk[r]) |
                         ((pk[r][3] & KMASK) <= thrk[r]);
        if (any) {
            const float A32 = s_A[prow];        // precomputed, bit-identical
            #pragma unroll
            for (int s = 0; s < 4; ++s) {
                if ((pk[r][s] & KMASK) <= thrk[r]) {
                    const int kc = (int)(pk[r][s] & 1023u);
                    const float* e = emb + (size_t)kc * D_DIM;
                    // B: GEMM-style single-accumulator SEQUENTIAL FMA over d.
                    float B32 = 0.f;
                    for (int d = 0; d < D_DIM; ++d)
                        B32 = ffma_x(s_zT[prow][d], e[d], B32);
                    const float twoB = fmul_x(2.0f, B32);      // exact
                    const float q    = fadd_x(fsub_x(A32, twoB), snorm[kc]);
                    // q = ||z-e||^2 ~ ||z||^2 > 0: positive-float uint order OK.
                    const unsigned long long p =
                        ((unsigned long long)__float_as_uint(q) << 32) |
                        (unsigned)kc;          // low bits = k: first-index tie-break
                    packq = (p < packq) ? p : packq;
                }
            }
        }
        // convergent 16-lane min-combine of packed (q,k)
        #pragma unroll
        for (int mask = 1; mask < 16; mask <<= 1) {
            const unsigned long long o = __shfl_xor(packq, mask, 64);
            packq = (o < packq) ? o : packq;
        }
        if (lm == 0) s_pk64[half][prow] = packq;
    }
    __syncthreads();

    // ---- cross-half final argmin ----
    if (tid < PXB) {
        const unsigned long long p0q = s_pk64[0][tid];
        const unsigned long long p1q = s_pk64[1][tid];
        s_kwin[tid] = (int)((p0q < p1q ? p0q : p1q) & 0xffffffffu);
    }
    __syncthreads();

    // ---- epilogue: out0 = fl(fl(e-z)+z) (pinned), out1 = e ----
    const int p  = tid & 127;                   // pixel
    const int dg = tid >> 7;                    // d-eighth 0..7
    const int kwin = s_kwin[p];
    const float* er = emb + (size_t)kwin * D_DIM + dg * 16;
    float* o0 = out + (size_t)b * (D_DIM * HW_SZ) + hw0 + p;
    float* o1 = o0 + OUT_OFF;
    #pragma unroll
    for (int i = 0; i < 4; ++i) {
        const f32x4 e4 = *(const f32x4*)(er + i * 4);
        #pragma unroll
        for (int j = 0; j < 4; ++j) {
            const int d = dg * 16 + i * 4 + j;
            const float zv = s_zT[p][d];
            o0[(size_t)d * HW_SZ] = fadd_x(fsub_x(e4[j], zv), zv);
            o1[(size_t)d * HW_SZ] = e4[j];
        }
    }
}

extern "C" void kernel_launch(void* const* d_in, const int* in_sizes, int n_in,
                              void* d_out, int out_size, void* d_ws, size_t ws_size,
                              hipStream_t stream)
{
    const float* z_e = (const float*)d_in[0];
    const float* emb = (const float*)d_in[1];
    float* out = (float*)d_out;
    float* sn_ws = (float*)d_ws;
    (void)in_sizes; (void)n_in; (void)out_size; (void)ws_size;

    snorm_pre<<<dim3(K_CODES / 256), dim3(256), 0, stream>>>(emb, sn_ws);
    vq_fused<<<dim3(N_PIX / PXB), dim3(64, NW), 0, stream>>>(z_e, emb, sn_ws, out);
}